// Round 8
// baseline (118.126 us; speedup 1.0000x reference)
//
#include <hip/hip_runtime.h>

// RasterizeGaussians: P=8192 gaussians -> 3x256x256 fp32 image.
// Stage 1: preprocess -> per-gaussian record + tile bbox; zeroes mask region
// Stage 2: O(P^2) rank sort + permute + per-(tile,chunk) rank-bitmask build
// Stage 3: per 8x8-px tile, 4 waves x 8 rank-chunks each: s_load mask words,
//          ffsll-walk set bits, compose directly from L2 (no LDS staging),
//          associative segment fold. XOR band swizzle kept from R6.

#define PN 8192
#define IH 256
#define IW 256

// ws float layout:
//  depth  [0, PN)
//  preA f4 [PN, 5PN)      (mx, my, cA, cB)
//  preB f4 [5PN, 9PN)     (cC, op, r, g)
//  preb    [9PN, 10PN)    (b color)
//  prebox  [10PN, 11PN)   (packed u32 tile bbox: x0|x1<<8|y0<<16|y1<<24)
//  sA f4   [11PN, 15PN)
//  sB f4   [15PN, 19PN)
//  sb      [19PN, 20PN)
//  (gap)   [20PN, 21PN)
//  mask    u64[1024][128] at float-idx 21PN (1 MB): tile*128 + (rank>>6)

#define WS_MASK (21 * PN)

__global__ __launch_bounds__(256) void preprocess_kernel(
    const float* __restrict__ means, const float* __restrict__ colors,
    const float* __restrict__ ops, const float* __restrict__ scales,
    const float* __restrict__ rots, const float* __restrict__ V,
    const float* __restrict__ Pm, float* __restrict__ ws)
{
    int i = blockIdx.x * 256 + threadIdx.x;
    if (i >= PN) return;

    // zero the 1 MB mask region: 8192 threads x 8 float4 = 1 MB
    {
        float4 z = make_float4(0.f, 0.f, 0.f, 0.f);
        float4* mz = (float4*)(ws + WS_MASK) + i * 8;
#pragma unroll
        for (int k = 0; k < 8; ++k) mz[k] = z;
    }

    float mx3 = means[3 * i], my3 = means[3 * i + 1], mz3 = means[3 * i + 2];
    float qr = rots[4 * i], qx = rots[4 * i + 1], qy = rots[4 * i + 2], qz = rots[4 * i + 3];
    float qn = 1.0f / sqrtf(qr * qr + qx * qx + qy * qy + qz * qz);
    float r = qr * qn, x = qx * qn, y = qy * qn, z = qz * qn;

    float R00 = 1.f - 2.f * (y * y + z * z), R01 = 2.f * (x * y - r * z), R02 = 2.f * (x * z + r * y);
    float R10 = 2.f * (x * y + r * z), R11 = 1.f - 2.f * (x * x + z * z), R12 = 2.f * (y * z - r * x);
    float R20 = 2.f * (x * z - r * y), R21 = 2.f * (y * z + r * x), R22 = 1.f - 2.f * (x * x + y * y);

    float s0 = scales[3 * i];     s0 *= s0;
    float s1 = scales[3 * i + 1]; s1 *= s1;
    float s2 = scales[3 * i + 2]; s2 *= s2;

    float Sg[3][3];
    Sg[0][0] = R00 * R00 * s0 + R01 * R01 * s1 + R02 * R02 * s2;
    Sg[0][1] = R00 * R10 * s0 + R01 * R11 * s1 + R02 * R12 * s2;
    Sg[0][2] = R00 * R20 * s0 + R01 * R21 * s1 + R02 * R22 * s2;
    Sg[1][1] = R10 * R10 * s0 + R11 * R11 * s1 + R12 * R12 * s2;
    Sg[1][2] = R10 * R20 * s0 + R11 * R21 * s1 + R12 * R22 * s2;
    Sg[2][2] = R20 * R20 * s0 + R21 * R21 * s1 + R22 * R22 * s2;
    Sg[1][0] = Sg[0][1]; Sg[2][0] = Sg[0][2]; Sg[2][1] = Sg[1][2];

    float pv0 = mx3 * V[0] + my3 * V[4] + mz3 * V[8]  + V[12];
    float pv1 = mx3 * V[1] + my3 * V[5] + mz3 * V[9]  + V[13];
    float pv2 = mx3 * V[2] + my3 * V[6] + mz3 * V[10] + V[14];
    float ph0 = mx3 * Pm[0] + my3 * Pm[4] + mz3 * Pm[8]  + Pm[12];
    float ph1 = mx3 * Pm[1] + my3 * Pm[5] + mz3 * Pm[9]  + Pm[13];
    float ph3 = mx3 * Pm[3] + my3 * Pm[7] + mz3 * Pm[11] + Pm[15];
    float pw = 1.0f / (ph3 + 1e-7f);
    float m2x = ((ph0 * pw + 1.0f) * (float)IW - 1.0f) * 0.5f;
    float m2y = ((ph1 * pw + 1.0f) * (float)IH - 1.0f) * 0.5f;

    float Rv[3][3];
#pragma unroll
    for (int rr = 0; rr < 3; ++rr)
#pragma unroll
        for (int cc2 = 0; cc2 < 3; ++cc2) Rv[rr][cc2] = V[rr * 4 + cc2];
    float M[3][3];
#pragma unroll
    for (int j = 0; j < 3; ++j)
#pragma unroll
        for (int l = 0; l < 3; ++l)
            M[j][l] = Sg[j][0] * Rv[0][l] + Sg[j][1] * Rv[1][l] + Sg[j][2] * Rv[2][l];
    float cc[3][3];
#pragma unroll
    for (int ii = 0; ii < 3; ++ii)
#pragma unroll
        for (int l = 0; l < 3; ++l)
            cc[ii][l] = Rv[0][ii] * M[0][l] + Rv[1][ii] * M[1][l] + Rv[2][ii] * M[2][l];

    const float FX = 256.0f, FY = 256.0f;
    float tz = pv2;
    float itz = 1.0f / tz;
    float limx = 0.65f, limy = 0.65f;
    float txz = fminf(fmaxf(pv0 * itz, -limx), limx);
    float tyz = fminf(fmaxf(pv1 * itz, -limy), limy);
    float tx = txz * tz, ty = tyz * tz;
    float J00 = FX * itz, J02 = -FX * tx * itz * itz;
    float J11 = FY * itz, J12 = -FY * ty * itz * itz;

    float u00 = J00 * cc[0][0] + J02 * cc[2][0];
    float u01 = J00 * cc[0][1] + J02 * cc[2][1];
    float u02 = J00 * cc[0][2] + J02 * cc[2][2];
    float u11 = J11 * cc[1][1] + J12 * cc[2][1];
    float u12 = J11 * cc[1][2] + J12 * cc[2][2];
    float cov00 = u00 * J00 + u02 * J02;
    float cov01 = u01 * J11 + u02 * J12;
    float cov11 = u11 * J11 + u12 * J12;

    float a = cov00 + 0.3f;
    float b = cov01;
    float c = cov11 + 0.3f;
    float det = a * c - b * b;
    float idet = 1.0f / det;
    float cA = c * idet;
    float cB = -b * idet;
    float cC = a * idet;

    float ex = sqrtf(11.2f * a);
    float ey = sqrtf(11.2f * c);
    int x0 = max(0,  (int)floorf((m2x - ex) * 0.125f));
    int x1 = min(31, (int)floorf((m2x + ex) * 0.125f));
    int y0 = max(0,  (int)floorf((m2y - ey) * 0.125f));
    int y1 = min(31, (int)floorf((m2y + ey) * 0.125f));
    x0 = min(x0, 31); y0 = min(y0, 31); x1 = max(x1, 0); y1 = max(y1, 0);
    unsigned box = (unsigned)x0 | ((unsigned)x1 << 8) | ((unsigned)y0 << 16) | ((unsigned)y1 << 24);

    ws[i] = pv2;  // depth
    float4* preA = (float4*)(ws + PN);
    float4* preB = (float4*)(ws + 5 * PN);
    preA[i] = make_float4(m2x, m2y, cA, cB);
    preB[i] = make_float4(cC, ops[i], colors[3 * i], colors[3 * i + 1]);
    ws[9 * PN + i] = colors[3 * i + 2];
    ((unsigned*)(ws + 10 * PN))[i] = box;
}

__global__ __launch_bounds__(256) void sort_scatter_kernel(float* __restrict__ ws)
{
    const float* dep = ws;
    const float4* d4 = (const float4*)ws;
    int lane = threadIdx.x & 63;
    int wid = threadIdx.x >> 6;
    int gbase = blockIdx.x * 16 + wid * 4;

    float di0 = dep[gbase], di1 = dep[gbase + 1], di2 = dep[gbase + 2], di3 = dep[gbase + 3];
    int r0 = 0, r1 = 0, r2 = 0, r3 = 0;
#pragma unroll 4
    for (int k = 0; k < 32; ++k) {
        int j4 = k * 64 + lane;
        float4 d = d4[j4];
        int jb = j4 * 4;
        r0 += (d.x < di0) || (d.x == di0 && (jb    ) < gbase);
        r0 += (d.y < di0) || (d.y == di0 && (jb + 1) < gbase);
        r0 += (d.z < di0) || (d.z == di0 && (jb + 2) < gbase);
        r0 += (d.w < di0) || (d.w == di0 && (jb + 3) < gbase);
        r1 += (d.x < di1) || (d.x == di1 && (jb    ) < gbase + 1);
        r1 += (d.y < di1) || (d.y == di1 && (jb + 1) < gbase + 1);
        r1 += (d.z < di1) || (d.z == di1 && (jb + 2) < gbase + 1);
        r1 += (d.w < di1) || (d.w == di1 && (jb + 3) < gbase + 1);
        r2 += (d.x < di2) || (d.x == di2 && (jb    ) < gbase + 2);
        r2 += (d.y < di2) || (d.y == di2 && (jb + 1) < gbase + 2);
        r2 += (d.z < di2) || (d.z == di2 && (jb + 2) < gbase + 2);
        r2 += (d.w < di2) || (d.w == di2 && (jb + 3) < gbase + 2);
        r3 += (d.x < di3) || (d.x == di3 && (jb    ) < gbase + 3);
        r3 += (d.y < di3) || (d.y == di3 && (jb + 1) < gbase + 3);
        r3 += (d.z < di3) || (d.z == di3 && (jb + 2) < gbase + 3);
        r3 += (d.w < di3) || (d.w == di3 && (jb + 3) < gbase + 3);
    }
#pragma unroll
    for (int off = 1; off < 64; off <<= 1) {
        r0 += __shfl_xor(r0, off);
        r1 += __shfl_xor(r1, off);
        r2 += __shfl_xor(r2, off);
        r3 += __shfl_xor(r3, off);
    }
    // after the butterfly every lane holds the full ranks r0..r3.

    if (lane < 4) {
        int rk = (lane == 0) ? r0 : (lane == 1) ? r1 : (lane == 2) ? r2 : r3;
        int i = gbase + lane;
        const float4* preA = (const float4*)(ws + PN);
        const float4* preB = (const float4*)(ws + 5 * PN);
        float4* sA = (float4*)(ws + 11 * PN);
        float4* sB = (float4*)(ws + 15 * PN);
        sA[rk] = preA[i];
        sB[rk] = preB[i];
        ws[19 * PN + rk] = ws[9 * PN + i];
    }

    // per-(tile,chunk) rank-bitmask build: all 64 lanes split the covered
    // tile rect of each of the wave's 4 gaussians; fire-and-forget atomics.
    const unsigned* prebox = (const unsigned*)(ws + 10 * PN);
    unsigned long long* msk = (unsigned long long*)(ws + WS_MASK);
    int rks[4] = {r0, r1, r2, r3};
#pragma unroll
    for (int j = 0; j < 4; ++j) {
        unsigned bx = prebox[gbase + j];   // uniform address -> broadcast
        int x0 = (int)(bx & 255), x1 = (int)((bx >> 8) & 255);
        int y0 = (int)((bx >> 16) & 255), y1 = (int)(bx >> 24);
        int nx = x1 - x0 + 1;
        int n = nx * (y1 - y0 + 1);
        int rk = rks[j];
        unsigned long long bit = 1ull << (rk & 63);
        int word = rk >> 6;                 // = chunk*4 + word-in-chunk
        for (int t = lane; t < n; t += 64) {
            int tyi = y0 + t / nx, txi = x0 + t % nx;
            atomicOr(&msk[(tyi * 32 + txi) * 128 + word], bit);
        }
    }
}

// 4 waves/block; wave w composes rank-chunks [8w, 8w+8) by walking the
// precomputed mask; reads gaussian records straight from L2 (uniform index
// -> cacheline broadcast). LDS only for the 4-segment fold (4 KB).
__global__ __launch_bounds__(256) void raster_kernel(
    const float* __restrict__ ws, const float* __restrict__ bg,
    float* __restrict__ out)
{
    __shared__ float seg[4][256];           // per-wave (ar,ag,ab,T) per pixel
    volatile __shared__ float waveT[4];     // monotone-decreasing max-T per wave

    int tid = threadIdx.x;
    int lane = tid & 63, w = tid >> 6;
    // XOR band swizzle (bijective): b=(q,r) -> tile=(q<<8)|(r^cq), cq=(q*9)&31
    int bq = blockIdx.x >> 8;
    int tileIdx = (bq << 8) | ((blockIdx.x & 255) ^ ((bq * 9) & 31));
    int tileX = tileIdx & 31, tileY = tileIdx >> 5;
    int px = tileX * 8 + (lane & 7), py = tileY * 8 + (lane >> 3);
    float pxf = (float)px, pyf = (float)py;

    const float4* sA = (const float4*)(ws + 11 * PN);
    const float4* sB = (const float4*)(ws + 15 * PN);
    const float* sb = ws + 19 * PN;
    const unsigned long long* msk =
        (const unsigned long long*)(ws + WS_MASK) + (size_t)tileIdx * 128;

    if (tid < 4) waveT[tid] = 1.0f;
    __syncthreads();  // uniform

    float T = 1.0f, ar = 0.0f, ag = 0.0f, ab = 0.0f;

    for (int chunk = w * 8; chunk < w * 8 + 8; ++chunk) {
        // conservative cross-wave exit: stale waveT reads are upper bounds.
        float pre = 1.0f;
        for (int q = 0; q < w; ++q) pre *= waveT[q];
        if (pre < 1e-4f) break;

        // uniform (blockIdx/loop-derived) addresses -> scalar loads
        unsigned long long m0 = msk[chunk * 4 + 0];
        unsigned long long m1 = msk[chunk * 4 + 1];
        unsigned long long m2 = msk[chunk * 4 + 2];
        unsigned long long m3 = msk[chunk * 4 + 3];
        if (!(m0 | m1 | m2 | m3)) continue;

        int base = chunk * 256;
        unsigned long long mv[4] = {m0, m1, m2, m3};
#pragma unroll
        for (int k = 0; k < 4; ++k) {
            unsigned long long wk = mv[k];
            while (wk) {
                int b = __ffsll((long long)wk) - 1;
                wk &= wk - 1;
                int g = base + k * 64 + b;
                float4 A = sA[g];           // uniform -> broadcast
                float4 B = sB[g];
                float bcol = sb[g];
                float dx = A.x - pxf, dy = A.y - pyf;
                float power = -0.5f * (A.z * dx * dx + B.x * dy * dy) - A.w * dx * dy;
                float alpha = fminf(0.99f, B.y * __expf(power));
                bool skip = (power > 0.0f) | (alpha < (1.0f / 255.0f));
                float a2 = skip ? 0.0f : alpha;
                float wgt = a2 * T;
                ar = fmaf(wgt, B.z, ar);
                ag = fmaf(wgt, B.w, ag);
                ab = fmaf(wgt, bcol, ab);
                T *= (1.0f - a2);
            }
        }

        if (__all(T < 1e-5f)) break;  // segment residual <= 1e-5

        float tmax = T;
#pragma unroll
        for (int off = 1; off < 64; off <<= 1) tmax = fmaxf(tmax, __shfl_xor(tmax, off));
        if (lane == 0) waveT[w] = tmax;
    }

    // segment fold: (A,T) compose left-to-right across the 4 waves
    seg[w][lane * 4 + 0] = ar;
    seg[w][lane * 4 + 1] = ag;
    seg[w][lane * 4 + 2] = ab;
    seg[w][lane * 4 + 3] = T;
    __syncthreads();  // uniform

    if (w == 0) {
        float A0 = 0.f, A1 = 0.f, A2 = 0.f, Tt = 1.f;
#pragma unroll
        for (int q = 0; q < 4; ++q) {
            A0 += Tt * seg[q][lane * 4 + 0];
            A1 += Tt * seg[q][lane * 4 + 1];
            A2 += Tt * seg[q][lane * 4 + 2];
            Tt *= seg[q][lane * 4 + 3];
        }
        int pidx = py * IW + px;
        out[pidx]               = A0 + Tt * bg[0];
        out[IH * IW + pidx]     = A1 + Tt * bg[1];
        out[2 * IH * IW + pidx] = A2 + Tt * bg[2];
    }
}

extern "C" void kernel_launch(void* const* d_in, const int* in_sizes, int n_in,
                              void* d_out, int out_size, void* d_ws, size_t ws_size,
                              hipStream_t stream) {
    const float* means  = (const float*)d_in[0];
    const float* colors = (const float*)d_in[1];
    const float* ops    = (const float*)d_in[2];
    const float* scales = (const float*)d_in[3];
    const float* rots   = (const float*)d_in[4];
    const float* bg     = (const float*)d_in[5];
    const float* viewm  = (const float*)d_in[6];
    const float* projm  = (const float*)d_in[7];
    float* out = (float*)d_out;
    float* ws  = (float*)d_ws;

    hipLaunchKernelGGL(preprocess_kernel, dim3(PN / 256), dim3(256), 0, stream,
                       means, colors, ops, scales, rots, viewm, projm, ws);
    hipLaunchKernelGGL(sort_scatter_kernel, dim3(PN / 16), dim3(256), 0, stream, ws);
    hipLaunchKernelGGL(raster_kernel, dim3(1024), dim3(256), 0, stream, ws, bg, out);
}

// Round 9
// 106.304 us; speedup vs baseline: 1.1112x; 1.1112x over previous
//
#include <hip/hip_runtime.h>

// RasterizeGaussians: P=8192 gaussians -> 3x256x256 fp32 image.
// Stage 1: preprocess -> per-gaussian record + tile bbox      [32 x 256]
// Stage 2: O(P^2) rank sort, wave-per-4-gaussians, permute    [512 x 256]
// Stage 3: one block = TWO complementary tiles (x and x+16, same y):
//          column density f(x)+f(x+16) ~ const -> block work ~ uniform.
//          8 waves/block: waves 0-3 quarter tile1, 4-7 quarter tile2;
//          4-wide compose; associative segment fold per tile.  [512 x 512]

#define PN 8192
#define IH 256
#define IW 256

// ws float layout:
//  depth  [0, PN)
//  preA f4 [PN, 5PN)      (mx, my, cA, cB)
//  preB f4 [5PN, 9PN)     (cC, op, r, g)
//  preb    [9PN, 10PN)    (b color)
//  prebox  [10PN, 11PN)   (packed u32 tile bbox: x0|x1<<8|y0<<16|y1<<24)
//  sA f4   [11PN, 15PN)
//  sB f4   [15PN, 19PN)
//  sb      [19PN, 20PN)
//  sbox    [20PN, 21PN)

__global__ __launch_bounds__(256) void preprocess_kernel(
    const float* __restrict__ means, const float* __restrict__ colors,
    const float* __restrict__ ops, const float* __restrict__ scales,
    const float* __restrict__ rots, const float* __restrict__ V,
    const float* __restrict__ Pm, float* __restrict__ ws)
{
    int i = blockIdx.x * 256 + threadIdx.x;
    if (i >= PN) return;

    float mx3 = means[3 * i], my3 = means[3 * i + 1], mz3 = means[3 * i + 2];
    float qr = rots[4 * i], qx = rots[4 * i + 1], qy = rots[4 * i + 2], qz = rots[4 * i + 3];
    float qn = 1.0f / sqrtf(qr * qr + qx * qx + qy * qy + qz * qz);
    float r = qr * qn, x = qx * qn, y = qy * qn, z = qz * qn;

    float R00 = 1.f - 2.f * (y * y + z * z), R01 = 2.f * (x * y - r * z), R02 = 2.f * (x * z + r * y);
    float R10 = 2.f * (x * y + r * z), R11 = 1.f - 2.f * (x * x + z * z), R12 = 2.f * (y * z - r * x);
    float R20 = 2.f * (x * z - r * y), R21 = 2.f * (y * z + r * x), R22 = 1.f - 2.f * (x * x + y * y);

    float s0 = scales[3 * i];     s0 *= s0;
    float s1 = scales[3 * i + 1]; s1 *= s1;
    float s2 = scales[3 * i + 2]; s2 *= s2;

    float Sg[3][3];
    Sg[0][0] = R00 * R00 * s0 + R01 * R01 * s1 + R02 * R02 * s2;
    Sg[0][1] = R00 * R10 * s0 + R01 * R11 * s1 + R02 * R12 * s2;
    Sg[0][2] = R00 * R20 * s0 + R01 * R21 * s1 + R02 * R22 * s2;
    Sg[1][1] = R10 * R10 * s0 + R11 * R11 * s1 + R12 * R12 * s2;
    Sg[1][2] = R10 * R20 * s0 + R11 * R21 * s1 + R12 * R22 * s2;
    Sg[2][2] = R20 * R20 * s0 + R21 * R21 * s1 + R22 * R22 * s2;
    Sg[1][0] = Sg[0][1]; Sg[2][0] = Sg[0][2]; Sg[2][1] = Sg[1][2];

    float pv0 = mx3 * V[0] + my3 * V[4] + mz3 * V[8]  + V[12];
    float pv1 = mx3 * V[1] + my3 * V[5] + mz3 * V[9]  + V[13];
    float pv2 = mx3 * V[2] + my3 * V[6] + mz3 * V[10] + V[14];
    float ph0 = mx3 * Pm[0] + my3 * Pm[4] + mz3 * Pm[8]  + Pm[12];
    float ph1 = mx3 * Pm[1] + my3 * Pm[5] + mz3 * Pm[9]  + Pm[13];
    float ph3 = mx3 * Pm[3] + my3 * Pm[7] + mz3 * Pm[11] + Pm[15];
    float pw = 1.0f / (ph3 + 1e-7f);
    float m2x = ((ph0 * pw + 1.0f) * (float)IW - 1.0f) * 0.5f;
    float m2y = ((ph1 * pw + 1.0f) * (float)IH - 1.0f) * 0.5f;

    float Rv[3][3];
#pragma unroll
    for (int rr = 0; rr < 3; ++rr)
#pragma unroll
        for (int cc2 = 0; cc2 < 3; ++cc2) Rv[rr][cc2] = V[rr * 4 + cc2];
    float M[3][3];
#pragma unroll
    for (int j = 0; j < 3; ++j)
#pragma unroll
        for (int l = 0; l < 3; ++l)
            M[j][l] = Sg[j][0] * Rv[0][l] + Sg[j][1] * Rv[1][l] + Sg[j][2] * Rv[2][l];
    float cc[3][3];
#pragma unroll
    for (int ii = 0; ii < 3; ++ii)
#pragma unroll
        for (int l = 0; l < 3; ++l)
            cc[ii][l] = Rv[0][ii] * M[0][l] + Rv[1][ii] * M[1][l] + Rv[2][ii] * M[2][l];

    const float FX = 256.0f, FY = 256.0f;
    float tz = pv2;
    float itz = 1.0f / tz;
    float limx = 0.65f, limy = 0.65f;
    float txz = fminf(fmaxf(pv0 * itz, -limx), limx);
    float tyz = fminf(fmaxf(pv1 * itz, -limy), limy);
    float tx = txz * tz, ty = tyz * tz;
    float J00 = FX * itz, J02 = -FX * tx * itz * itz;
    float J11 = FY * itz, J12 = -FY * ty * itz * itz;

    float u00 = J00 * cc[0][0] + J02 * cc[2][0];
    float u01 = J00 * cc[0][1] + J02 * cc[2][1];
    float u02 = J00 * cc[0][2] + J02 * cc[2][2];
    float u11 = J11 * cc[1][1] + J12 * cc[2][1];
    float u12 = J11 * cc[1][2] + J12 * cc[2][2];
    float cov00 = u00 * J00 + u02 * J02;
    float cov01 = u01 * J11 + u02 * J12;
    float cov11 = u11 * J11 + u12 * J12;

    float a = cov00 + 0.3f;
    float b = cov01;
    float c = cov11 + 0.3f;
    float det = a * c - b * b;
    float idet = 1.0f / det;
    float cA = c * idet;
    float cB = -b * idet;
    float cC = a * idet;

    float ex = sqrtf(11.2f * a);
    float ey = sqrtf(11.2f * c);
    int x0 = max(0,  (int)floorf((m2x - ex) * 0.125f));
    int x1 = min(31, (int)floorf((m2x + ex) * 0.125f));
    int y0 = max(0,  (int)floorf((m2y - ey) * 0.125f));
    int y1 = min(31, (int)floorf((m2y + ey) * 0.125f));
    x0 = min(x0, 31); y0 = min(y0, 31); x1 = max(x1, 0); y1 = max(y1, 0);
    unsigned box = (unsigned)x0 | ((unsigned)x1 << 8) | ((unsigned)y0 << 16) | ((unsigned)y1 << 24);

    ws[i] = pv2;  // depth
    float4* preA = (float4*)(ws + PN);
    float4* preB = (float4*)(ws + 5 * PN);
    preA[i] = make_float4(m2x, m2y, cA, cB);
    preB[i] = make_float4(cC, ops[i], colors[3 * i], colors[3 * i + 1]);
    ws[9 * PN + i] = colors[3 * i + 2];
    ((unsigned*)(ws + 10 * PN))[i] = box;
}

__global__ __launch_bounds__(256) void sort_scatter_kernel(float* __restrict__ ws)
{
    const float* dep = ws;
    const float4* d4 = (const float4*)ws;
    int lane = threadIdx.x & 63;
    int wid = threadIdx.x >> 6;
    int gbase = blockIdx.x * 16 + wid * 4;

    float di0 = dep[gbase], di1 = dep[gbase + 1], di2 = dep[gbase + 2], di3 = dep[gbase + 3];
    int r0 = 0, r1 = 0, r2 = 0, r3 = 0;
#pragma unroll 4
    for (int k = 0; k < 32; ++k) {
        int j4 = k * 64 + lane;
        float4 d = d4[j4];
        int jb = j4 * 4;
        r0 += (d.x < di0) || (d.x == di0 && (jb    ) < gbase);
        r0 += (d.y < di0) || (d.y == di0 && (jb + 1) < gbase);
        r0 += (d.z < di0) || (d.z == di0 && (jb + 2) < gbase);
        r0 += (d.w < di0) || (d.w == di0 && (jb + 3) < gbase);
        r1 += (d.x < di1) || (d.x == di1 && (jb    ) < gbase + 1);
        r1 += (d.y < di1) || (d.y == di1 && (jb + 1) < gbase + 1);
        r1 += (d.z < di1) || (d.z == di1 && (jb + 2) < gbase + 1);
        r1 += (d.w < di1) || (d.w == di1 && (jb + 3) < gbase + 1);
        r2 += (d.x < di2) || (d.x == di2 && (jb    ) < gbase + 2);
        r2 += (d.y < di2) || (d.y == di2 && (jb + 1) < gbase + 2);
        r2 += (d.z < di2) || (d.z == di2 && (jb + 2) < gbase + 2);
        r2 += (d.w < di2) || (d.w == di2 && (jb + 3) < gbase + 2);
        r3 += (d.x < di3) || (d.x == di3 && (jb    ) < gbase + 3);
        r3 += (d.y < di3) || (d.y == di3 && (jb + 1) < gbase + 3);
        r3 += (d.z < di3) || (d.z == di3 && (jb + 2) < gbase + 3);
        r3 += (d.w < di3) || (d.w == di3 && (jb + 3) < gbase + 3);
    }
#pragma unroll
    for (int off = 1; off < 64; off <<= 1) {
        r0 += __shfl_xor(r0, off);
        r1 += __shfl_xor(r1, off);
        r2 += __shfl_xor(r2, off);
        r3 += __shfl_xor(r3, off);
    }
    if (lane < 4) {
        int rk = (lane == 0) ? r0 : (lane == 1) ? r1 : (lane == 2) ? r2 : r3;
        int i = gbase + lane;
        const float4* preA = (const float4*)(ws + PN);
        const float4* preB = (const float4*)(ws + 5 * PN);
        float4* sA = (float4*)(ws + 11 * PN);
        float4* sB = (float4*)(ws + 15 * PN);
        sA[rk] = preA[i];
        sB[rk] = preB[i];
        ws[19 * PN + rk] = ws[9 * PN + i];
        ((unsigned*)(ws + 20 * PN))[rk] = ((const unsigned*)(ws + 10 * PN))[i];
    }
}

// One block = two complementary tiles (x, y) and (x+16, y). 8 waves:
// wave w: tile group g=w>>2, chunk quarter wl=w&3 -> chunks [8wl, 8wl+8).
// LDS 72 KB -> 2 blocks/CU; 512 blocks x 8 waves = full chip residency.
__global__ __launch_bounds__(512, 4) void raster_kernel(
    const float* __restrict__ ws, const float* __restrict__ bg,
    float* __restrict__ out)
{
    __shared__ float4 lsA[8][256];          // 32 KB
    __shared__ float4 lsB[8][256];          // 32 KB
    __shared__ float  lsb[8][256];          // 8 KB; seg state overlay after loop
    volatile __shared__ float waveT[8];     // monotone-decreasing max-T per wave

    int tid = threadIdx.x;
    int lane = tid & 63, w = tid >> 6;      // w in [0,8)
    int g = w >> 2, wl = w & 3;             // tile group, chunk quarter
    int yt = blockIdx.x >> 4;               // 0..31
    int xh = blockIdx.x & 15;               // 0..15
    int tileX = xh + g * 16, tileY = yt;    // tile1: x in [0,16); tile2: x+16
    int px = tileX * 8 + (lane & 7), py = tileY * 8 + (lane >> 3);
    float pxf = (float)px, pyf = (float)py;

    const float4* sA = (const float4*)(ws + 11 * PN);
    const float4* sB = (const float4*)(ws + 15 * PN);
    const float* sb = ws + 19 * PN;
    const unsigned* sbox = (const unsigned*)(ws + 20 * PN);

    if (tid < 8) waveT[tid] = 1.0f;
    __syncthreads();  // uniform

    float T = 1.0f, ar = 0.0f, ag = 0.0f, ab = 0.0f;

    for (int chunk = wl * 8; chunk < wl * 8 + 8; ++chunk) {
        // conservative cross-wave exit within this tile's 4-wave group:
        // stale waveT reads are upper bounds (monotone decreasing).
        float pre = 1.0f;
        for (int q = g * 4; q < w; ++q) pre *= waveT[q];
        if (pre < 1e-4f) break;

        int base = chunk * 256;
        unsigned long long wv[4];
#pragma unroll
        for (int k = 0; k < 4; ++k) {
            unsigned bx = sbox[base + k * 64 + lane];
            bool ov = (tileX >= (int)(bx & 255)) & (tileX <= (int)((bx >> 8) & 255)) &
                      (tileY >= (int)((bx >> 16) & 255)) & (tileY <= (int)(bx >> 24));
            wv[k] = __ballot(ov);
        }
        if (!(wv[0] | wv[1] | wv[2] | wv[3])) continue;

        int cnt = 0;
#pragma unroll
        for (int k = 0; k < 4; ++k) {
            unsigned long long wk = wv[k];
            if ((wk >> lane) & 1ull) {
                int slot = cnt + (int)__popcll(wk & ((1ull << lane) - 1ull));
                int gg = base + k * 64 + lane;
                lsA[w][slot] = sA[gg];
                lsB[w][slot] = sB[gg];
                lsb[w][slot] = sb[gg];
            }
            cnt += (int)__popcll(wk);
        }
        asm volatile("s_waitcnt lgkmcnt(0)" ::: "memory");  // wave-local LDS fence

        // 4-wide compose: (1-a) products tree-reassociated (fp-tiny diffs),
        // 4 exps in flight, T-chain depth ~3 per 4 evals.
        int j = 0;
        for (; j + 3 < cnt; j += 4) {
            float4 A0 = lsA[w][j],     B0 = lsB[w][j];
            float4 A1 = lsA[w][j + 1], B1 = lsB[w][j + 1];
            float4 A2 = lsA[w][j + 2], B2 = lsB[w][j + 2];
            float4 A3 = lsA[w][j + 3], B3 = lsB[w][j + 3];
            float c0 = lsb[w][j], c1 = lsb[w][j + 1], c2 = lsb[w][j + 2], c3 = lsb[w][j + 3];
            float dx0 = A0.x - pxf, dy0 = A0.y - pyf;
            float dx1 = A1.x - pxf, dy1 = A1.y - pyf;
            float dx2 = A2.x - pxf, dy2 = A2.y - pyf;
            float dx3 = A3.x - pxf, dy3 = A3.y - pyf;
            float p0 = -0.5f * (A0.z * dx0 * dx0 + B0.x * dy0 * dy0) - A0.w * dx0 * dy0;
            float p1 = -0.5f * (A1.z * dx1 * dx1 + B1.x * dy1 * dy1) - A1.w * dx1 * dy1;
            float p2 = -0.5f * (A2.z * dx2 * dx2 + B2.x * dy2 * dy2) - A2.w * dx2 * dy2;
            float p3 = -0.5f * (A3.z * dx3 * dx3 + B3.x * dy3 * dy3) - A3.w * dx3 * dy3;
            float e0 = fminf(0.99f, B0.y * __expf(p0));
            float e1 = fminf(0.99f, B1.y * __expf(p1));
            float e2 = fminf(0.99f, B2.y * __expf(p2));
            float e3 = fminf(0.99f, B3.y * __expf(p3));
            float a0 = ((p0 > 0.0f) | (e0 < (1.0f / 255.0f))) ? 0.0f : e0;
            float a1 = ((p1 > 0.0f) | (e1 < (1.0f / 255.0f))) ? 0.0f : e1;
            float a2 = ((p2 > 0.0f) | (e2 < (1.0f / 255.0f))) ? 0.0f : e2;
            float a3 = ((p3 > 0.0f) | (e3 < (1.0f / 255.0f))) ? 0.0f : e3;
            float t0 = 1.0f - a0, t1 = 1.0f - a1, t2 = 1.0f - a2, t3 = 1.0f - a3;
            float c01 = t0 * t1, c012 = c01 * t2;
            float w0 = a0 * T;
            float w1 = a1 * (T * t0);
            float w2 = a2 * (T * c01);
            float w3 = a3 * (T * c012);
            ar = fmaf(w0, B0.z, ar); ar = fmaf(w1, B1.z, ar);
            ar = fmaf(w2, B2.z, ar); ar = fmaf(w3, B3.z, ar);
            ag = fmaf(w0, B0.w, ag); ag = fmaf(w1, B1.w, ag);
            ag = fmaf(w2, B2.w, ag); ag = fmaf(w3, B3.w, ag);
            ab = fmaf(w0, c0, ab);   ab = fmaf(w1, c1, ab);
            ab = fmaf(w2, c2, ab);   ab = fmaf(w3, c3, ab);
            T *= (c012 * t3);
        }
        for (; j < cnt; ++j) {
            float4 A = lsA[w][j];
            float4 B = lsB[w][j];
            float bcol = lsb[w][j];
            float dx = A.x - pxf, dy = A.y - pyf;
            float power = -0.5f * (A.z * dx * dx + B.x * dy * dy) - A.w * dx * dy;
            float alpha = fminf(0.99f, B.y * __expf(power));
            float a2 = ((power > 0.0f) | (alpha < (1.0f / 255.0f))) ? 0.0f : alpha;
            float wgt = a2 * T;
            ar = fmaf(wgt, B.z, ar);
            ag = fmaf(wgt, B.w, ag);
            ab = fmaf(wgt, bcol, ab);
            T *= (1.0f - a2);
        }
        asm volatile("s_waitcnt lgkmcnt(0)" ::: "memory");  // WAR vs next compaction

        if (__all(T < 1e-5f)) break;  // segment residual <= 1e-5

        float tmax = T;
#pragma unroll
        for (int off = 1; off < 64; off <<= 1) tmax = fmaxf(tmax, __shfl_xor(tmax, off));
        if (lane == 0) waveT[w] = tmax;
    }

    // publish segment state into own lsb region (per-wave ownership -> race-free)
    lsb[w][lane * 4 + 0] = ar;
    lsb[w][lane * 4 + 1] = ag;
    lsb[w][lane * 4 + 2] = ab;
    lsb[w][lane * 4 + 3] = T;
    __syncthreads();  // uniform: every wave reaches here

    if (wl == 0) {   // waves 0 and 4 fold their tile's 4 segments
        float A0 = 0.f, A1 = 0.f, A2 = 0.f, Tt = 1.f;
#pragma unroll
        for (int q = 0; q < 4; ++q) {
            A0 += Tt * lsb[g * 4 + q][lane * 4 + 0];
            A1 += Tt * lsb[g * 4 + q][lane * 4 + 1];
            A2 += Tt * lsb[g * 4 + q][lane * 4 + 2];
            Tt *= lsb[g * 4 + q][lane * 4 + 3];
        }
        int pidx = py * IW + px;
        out[pidx]               = A0 + Tt * bg[0];
        out[IH * IW + pidx]     = A1 + Tt * bg[1];
        out[2 * IH * IW + pidx] = A2 + Tt * bg[2];
    }
}

extern "C" void kernel_launch(void* const* d_in, const int* in_sizes, int n_in,
                              void* d_out, int out_size, void* d_ws, size_t ws_size,
                              hipStream_t stream) {
    const float* means  = (const float*)d_in[0];
    const float* colors = (const float*)d_in[1];
    const float* ops    = (const float*)d_in[2];
    const float* scales = (const float*)d_in[3];
    const float* rots   = (const float*)d_in[4];
    const float* bg     = (const float*)d_in[5];
    const float* viewm  = (const float*)d_in[6];
    const float* projm  = (const float*)d_in[7];
    float* out = (float*)d_out;
    float* ws  = (float*)d_ws;

    hipLaunchKernelGGL(preprocess_kernel, dim3(PN / 256), dim3(256), 0, stream,
                       means, colors, ops, scales, rots, viewm, projm, ws);
    hipLaunchKernelGGL(sort_scatter_kernel, dim3(PN / 16), dim3(256), 0, stream, ws);
    hipLaunchKernelGGL(raster_kernel, dim3(512), dim3(512), 0, stream, ws, bg, out);
}